// Round 1
// baseline (3177.754 us; speedup 1.0000x reference)
//
#include <hip/hip_runtime.h>

#define B_ 256
#define T_ 1024
#define H_ 64

typedef float f32x2 __attribute__((ext_vector_type(2)));
typedef float f32x4 __attribute__((ext_vector_type(4)));

// fast sigmoid/tanh via v_exp_f32 + v_rcp_f32 (validated R2-R15: absmax 0.0)
__device__ __forceinline__ float fast_sigmoid(float x) {
    float e = __builtin_amdgcn_exp2f(-1.4426950408889634f * x);
    return __builtin_amdgcn_rcpf(1.0f + e);
}
__device__ __forceinline__ float fast_tanh(float x) {
    float e = __builtin_amdgcn_exp2f(2.8853900817779268f * x);
    return 1.0f - 2.0f * __builtin_amdgcn_rcpf(1.0f + e);
}

// butterfly add via DPP: 0xB1=xor1, 0x4E=xor2 (NCH=4 -> 2 stages, R8-validated)
template<int CTRL>
__device__ __forceinline__ float dpp_addf(float v) {
    int vi = __builtin_bit_cast(int, v);
    int sh = __builtin_amdgcn_update_dpp(0, vi, CTRL, 0xF, 0xF, true);
    return v + __builtin_bit_cast(float, sh);
}

__device__ __forceinline__ float hsum4(f32x4 v) { return (v.x + v.y) + (v.z + v.w); }

// ---- flag-based role synchronization (this round's change) ----
// Per-wave monotonic step counters in LDS (single-writer each). Roles gate on
// min over 4 counters; cross-role slack is bounded by 4-deep slot buffers.
__device__ __forceinline__ unsigned min4v(const volatile unsigned* c) {
    unsigned a = c[0], b = c[1], d = c[2], e = c[3];
    asm volatile("" ::: "memory");          // no hoisting of dependent LDS reads
    unsigned m0 = a < b ? a : b;
    unsigned m1 = d < e ? d : e;
    return m0 < m1 ? m0 : m1;
}
__device__ __forceinline__ void wait_ge(const volatile unsigned* c, unsigned tgt) {
    while (min4v(c) < tgt) {}
}
__device__ __forceinline__ void publish_cnt(volatile unsigned* slot, unsigned v,
                                            bool lane0) {
    // drain own ds_writes so data is in LDS before the flag becomes visible
    asm volatile("s_waitcnt lgkmcnt(0)" ::: "memory");
    if (lane0) *slot = v;
}

// ---- heavy role building blocks (R8/R12-validated geometry) ----
// thread = (j in [0,64), kc in [0,4)): 4 gate rows {r*64+j} x 32-float chunk
// of [x(0..63) | h(64..127)]; chunk kc at kc*36 floats (conflict-free b128).
__device__ __forceinline__ void load_w_heavy(const float* __restrict__ w_ih,
                                             const float* __restrict__ w_hh,
                                             int j, int kc, f32x4 wt[4][8]) {
    #pragma unroll
    for (int r = 0; r < 4; ++r) {
        const int row = r * H_ + j;
        const float* base = (kc < 2) ? (w_ih + row * H_ + kc * 32)
                                     : (w_hh + row * H_ + (kc - 2) * 32);
        #pragma unroll
        for (int q = 0; q < 8; ++q)
            wt[r][q] = *(const f32x4*)(base + 4 * q);
    }
    #pragma unroll
    for (int r = 0; r < 4; ++r)
        #pragma unroll
        for (int q = 0; q < 8; ++q)
            asm volatile("" : "+v"(wt[r][q]));
}

__device__ __forceinline__ void dot4x32(const float* chunk, const f32x4 wt[4][8],
                                        float acc[4]) {
    const f32x4* xv = (const f32x4*)chunk;
    f32x4 a0 = {0,0,0,0}, a1 = {0,0,0,0}, a2 = {0,0,0,0}, a3 = {0,0,0,0};
    #pragma unroll
    for (int q = 0; q < 8; ++q) {
        f32x4 hq = xv[q];
        a0 = __builtin_elementwise_fma(wt[0][q], hq, a0);
        a1 = __builtin_elementwise_fma(wt[1][q], hq, a1);
        a2 = __builtin_elementwise_fma(wt[2][q], hq, a2);
        a3 = __builtin_elementwise_fma(wt[3][q], hq, a3);
    }
    acc[0] = hsum4(a0); acc[1] = hsum4(a1);
    acc[2] = hsum4(a2); acc[3] = hsum4(a3);
}

// ---------------------------------------------------------------------------
// K1'': decoupled TRIPLE [L0+L1+L2]. Same math/geometry as R12 kernel, but
// the per-step s_barrier is replaced with per-role flag sync + 4-slot LDS
// buffers, letting the three role pipelines drift/anti-phase (slack <= 3).
// Slot convention: inputs for local step t live in slot t&3.
//   role r step t: reads own buf[t&3]; writes own h -> buf[(t+1)&3],
//   cross h -> next-role buf[t&3].x. Gates: own min>=t, producer min>=t+1,
//   consumer backpressure min>=t-3 (lazy, t>=4).
// ---------------------------------------------------------------------------
__global__ __attribute__((amdgpu_flat_work_group_size(768, 768)))
void lstm_tri012(const float* __restrict__ x,      // [B,T]
                 float* __restrict__ hout,         // [B,T,64] = h_L2
                 const float* __restrict__ w_ih0,  // [256]
                 const float* __restrict__ whh0,
                 const float* __restrict__ bih0, const float* __restrict__ bhh0,
                 const float* __restrict__ wih1, const float* __restrict__ whh1,
                 const float* __restrict__ bih1, const float* __restrict__ bhh1,
                 const float* __restrict__ wih2, const float* __restrict__ whh2,
                 const float* __restrict__ bih2, const float* __restrict__ bhh2)
{
    const int b    = blockIdx.x;
    const int tid  = threadIdx.x;
    const int role = tid >> 8;      // 0=L0, 1=L1, 2=L2 (wave-uniform)
    const int loc  = tid & 255;
    const int kc   = loc & 3;
    const int j    = loc >> 2;      // hidden unit
    const int wv   = (tid >> 6) & 3;        // wave id within role
    const bool lane0 = (tid & 63) == 0;

    __shared__ __align__(16) float bufL0[4][80];    // L0 h: 4 chunks x 20
    __shared__ __align__(16) float bufL1[4][144];   // [x|h]: 4 chunks x 36
    __shared__ __align__(16) float bufL2[4][144];
    __shared__ __align__(16) unsigned cnts[3][4];   // per-role per-wave step count

    f32x4 wt[4][8];                 // L0 uses [4][4] portion
    float bias0 = 0.f, bias1 = 0.f, bias2 = 0.f, bias3 = 0.f;
    float w00 = 0.f, w01 = 0.f, w02 = 0.f, w03 = 0.f;

    if (role == 0) {
        #pragma unroll
        for (int r = 0; r < 4; ++r) {
            const int row = r * H_ + j;
            const float* base = whh0 + row * H_ + kc * 16;
            #pragma unroll
            for (int q = 0; q < 4; ++q)
                wt[r][q] = *(const f32x4*)(base + 4 * q);
        }
        #pragma unroll
        for (int r = 0; r < 4; ++r)
            #pragma unroll
            for (int q = 0; q < 4; ++q)
                asm volatile("" : "+v"(wt[r][q]));
        if (kc == 0) {
            bias0 = bih0[0*H_+j] + bhh0[0*H_+j];
            bias1 = bih0[1*H_+j] + bhh0[1*H_+j];
            bias2 = bih0[2*H_+j] + bhh0[2*H_+j];
            bias3 = bih0[3*H_+j] + bhh0[3*H_+j];
            w00 = w_ih0[0*H_+j]; w01 = w_ih0[1*H_+j];
            w02 = w_ih0[2*H_+j]; w03 = w_ih0[3*H_+j];
        }
    } else {
        const float* wih = (role == 1) ? wih1 : wih2;
        const float* whh = (role == 1) ? whh1 : whh2;
        const float* bih = (role == 1) ? bih1 : bih2;
        const float* bhh = (role == 1) ? bhh1 : bhh2;
        load_w_heavy(wih, whh, j, kc, wt);
        if (kc == 0) {
            bias0 = bih[0*H_+j] + bhh[0*H_+j];
            bias1 = bih[1*H_+j] + bhh[1*H_+j];
            bias2 = bih[2*H_+j] + bhh[2*H_+j];
            bias3 = bih[3*H_+j] + bhh[3*H_+j];
        }
    }

    // init: all roles start local step 0 -> slot 0 holds h[-1]=0; counters 0.
    if (tid < 12) cnts[tid >> 2][tid & 3] = 0;
    if (loc < H_) {
        const int u = loc;
        if (role == 0)      bufL0[0][(u >> 4) * 20 + (u & 15)] = 0.f;
        else if (role == 1) bufL1[0][(2 + (u >> 5)) * 36 + (u & 31)] = 0.f;
        else                bufL2[0][(2 + (u >> 5)) * 36 + (u & 31)] = 0.f;
    }
    __syncthreads();

    if (role == 0) {
        float c_st = 0.f;
        float xt = x[(long)b * T_];
        unsigned bp = 0;                         // cached L1 progress
        for (int t = 0; t < T_; ++t) {
            float xn = 0.f;
            if (t + 1 < T_) xn = x[(long)b * T_ + t + 1];   // wave-uniform
            wait_ge(cnts[0], (unsigned)t);                   // own h[t-1] ready
            if (t >= 4) {                                    // bufL1[t&3].x reuse
                const unsigned need = (unsigned)(t - 3);
                while (bp < need) bp = min4v(cnts[1]);
            }
            const f32x4* xv = (const f32x4*)&bufL0[t & 3][kc * 20];
            f32x4 h0 = xv[0], h1 = xv[1], h2 = xv[2], h3 = xv[3];
            f32x4 a0 = {0,0,0,0}, a1 = {0,0,0,0}, a2 = {0,0,0,0}, a3 = {0,0,0,0};
            a0 = __builtin_elementwise_fma(wt[0][0], h0, a0);
            a1 = __builtin_elementwise_fma(wt[1][0], h0, a1);
            a2 = __builtin_elementwise_fma(wt[2][0], h0, a2);
            a3 = __builtin_elementwise_fma(wt[3][0], h0, a3);
            a0 = __builtin_elementwise_fma(wt[0][1], h1, a0);
            a1 = __builtin_elementwise_fma(wt[1][1], h1, a1);
            a2 = __builtin_elementwise_fma(wt[2][1], h1, a2);
            a3 = __builtin_elementwise_fma(wt[3][1], h1, a3);
            a0 = __builtin_elementwise_fma(wt[0][2], h2, a0);
            a1 = __builtin_elementwise_fma(wt[1][2], h2, a1);
            a2 = __builtin_elementwise_fma(wt[2][2], h2, a2);
            a3 = __builtin_elementwise_fma(wt[3][2], h2, a3);
            a0 = __builtin_elementwise_fma(wt[0][3], h3, a0);
            a1 = __builtin_elementwise_fma(wt[1][3], h3, a1);
            a2 = __builtin_elementwise_fma(wt[2][3], h3, a2);
            a3 = __builtin_elementwise_fma(wt[3][3], h3, a3);
            float acc0 = hsum4(a0), acc1 = hsum4(a1);
            float acc2 = hsum4(a2), acc3 = hsum4(a3);
            acc0 = dpp_addf<0xB1>(acc0); acc1 = dpp_addf<0xB1>(acc1);
            acc2 = dpp_addf<0xB1>(acc2); acc3 = dpp_addf<0xB1>(acc3);
            acc0 = dpp_addf<0x4E>(acc0); acc1 = dpp_addf<0x4E>(acc1);
            acc2 = dpp_addf<0x4E>(acc2); acc3 = dpp_addf<0x4E>(acc3);
            if (kc == 0) {
                float i_ = fast_sigmoid(acc0 + bias0 + w00 * xt);
                float f_ = fast_sigmoid(acc1 + bias1 + w01 * xt);
                float g_ = fast_tanh   (acc2 + bias2 + w02 * xt);
                float o_ = fast_sigmoid(acc3 + bias3 + w03 * xt);
                c_st = f_ * c_st + i_ * g_;
                float h = o_ * fast_tanh(c_st);
                bufL0[(t + 1) & 3][(j >> 4) * 20 + (j & 15)] = h;   // own h[t]
                bufL1[t & 3][(j >> 5) * 36 + (j & 31)] = h;         // L1 step-t x
            }
            publish_cnt(&cnts[0][wv], (unsigned)(t + 1), lane0);
            xt = xn;
        }
    } else if (role == 1) {
        float c_st = 0.f;
        unsigned pp = 0, bp = 0;                 // cached L0 / L2 progress
        for (int t = 0; t < T_; ++t) {
            wait_ge(cnts[1], (unsigned)t);                   // own h[t-1]
            { const unsigned need = (unsigned)(t + 1);       // x = h_L0[t]
              while (pp < need) pp = min4v(cnts[0]); }
            if (t >= 4) {                                    // bufL2[t&3].x reuse
                const unsigned need = (unsigned)(t - 3);
                while (bp < need) bp = min4v(cnts[2]);
            }
            float acc[4];
            dot4x32(&bufL1[t & 3][kc * 36], wt, acc);
            acc[0] = dpp_addf<0xB1>(acc[0]); acc[1] = dpp_addf<0xB1>(acc[1]);
            acc[2] = dpp_addf<0xB1>(acc[2]); acc[3] = dpp_addf<0xB1>(acc[3]);
            acc[0] = dpp_addf<0x4E>(acc[0]); acc[1] = dpp_addf<0x4E>(acc[1]);
            acc[2] = dpp_addf<0x4E>(acc[2]); acc[3] = dpp_addf<0x4E>(acc[3]);
            if (kc == 0) {
                float i_ = fast_sigmoid(acc[0] + bias0);
                float f_ = fast_sigmoid(acc[1] + bias1);
                float g_ = fast_tanh   (acc[2] + bias2);
                float o_ = fast_sigmoid(acc[3] + bias3);
                c_st = f_ * c_st + i_ * g_;
                float h = o_ * fast_tanh(c_st);
                bufL1[(t + 1) & 3][(2 + (j >> 5)) * 36 + (j & 31)] = h; // own h
                bufL2[t & 3][(j >> 5) * 36 + (j & 31)] = h;             // L2 x
            }
            publish_cnt(&cnts[1][wv], (unsigned)(t + 1), lane0);
        }
    } else {
        float c_st = 0.f;
        unsigned pp = 0;                          // cached L1 progress
        for (int t = 0; t < T_; ++t) {
            wait_ge(cnts[2], (unsigned)t);
            { const unsigned need = (unsigned)(t + 1);       // x = h_L1[t]
              while (pp < need) pp = min4v(cnts[1]); }
            float acc[4];
            dot4x32(&bufL2[t & 3][kc * 36], wt, acc);
            acc[0] = dpp_addf<0xB1>(acc[0]); acc[1] = dpp_addf<0xB1>(acc[1]);
            acc[2] = dpp_addf<0xB1>(acc[2]); acc[3] = dpp_addf<0xB1>(acc[3]);
            acc[0] = dpp_addf<0x4E>(acc[0]); acc[1] = dpp_addf<0x4E>(acc[1]);
            acc[2] = dpp_addf<0x4E>(acc[2]); acc[3] = dpp_addf<0x4E>(acc[3]);
            if (kc == 0) {
                float i_ = fast_sigmoid(acc[0] + bias0);
                float f_ = fast_sigmoid(acc[1] + bias1);
                float g_ = fast_tanh   (acc[2] + bias2);
                float o_ = fast_sigmoid(acc[3] + bias3);
                c_st = f_ * c_st + i_ * g_;
                float h = o_ * fast_tanh(c_st);
                bufL2[(t + 1) & 3][(2 + (j >> 5)) * 36 + (j & 31)] = h; // own h
                hout[((long)b * T_ + t) * H_ + j] = h;
            }
            publish_cnt(&cnts[2][wv], (unsigned)(t + 1), lane0);
        }
    }
}

// ---------------------------------------------------------------------------
// K2'': decoupled PAIR [L3+L4]. Same flag scheme; L3's x (= h_L2) is
// register-prefetched from global by kc==1 lanes and staged one slot ahead.
// ---------------------------------------------------------------------------
__global__ __attribute__((amdgpu_flat_work_group_size(512, 512)))
void lstm_pair34(const float* __restrict__ xin,   // [B,T,64] h_L2 (aliases hout)
                 float* __restrict__ hout,        // [B,T,64] h_L4
                 const float* __restrict__ wih3, const float* __restrict__ whh3,
                 const float* __restrict__ bih3, const float* __restrict__ bhh3,
                 const float* __restrict__ wih4, const float* __restrict__ whh4,
                 const float* __restrict__ bih4, const float* __restrict__ bhh4)
{
    const int b    = blockIdx.x;
    const int tid  = threadIdx.x;
    const int role = tid >> 8;      // 0=L3, 1=L4 (wave-uniform)
    const int loc  = tid & 255;
    const int kc   = loc & 3;
    const int j    = loc >> 2;
    const int wv   = (tid >> 6) & 3;
    const bool lane0 = (tid & 63) == 0;

    __shared__ __align__(16) float bufL3[4][144];
    __shared__ __align__(16) float bufL4[4][144];
    __shared__ __align__(16) unsigned cnts[2][4];

    const float* wih = (role == 0) ? wih3 : wih4;
    const float* whh = (role == 0) ? whh3 : whh4;
    const float* bih = (role == 0) ? bih3 : bih4;
    const float* bhh = (role == 0) ? bhh3 : bhh4;

    f32x4 wt[4][8];
    load_w_heavy(wih, whh, j, kc, wt);

    float bias0 = 0.f, bias1 = 0.f, bias2 = 0.f, bias3 = 0.f;
    if (kc == 0) {
        bias0 = bih[0*H_+j] + bhh[0*H_+j];
        bias1 = bih[1*H_+j] + bhh[1*H_+j];
        bias2 = bih[2*H_+j] + bhh[2*H_+j];
        bias3 = bih[3*H_+j] + bhh[3*H_+j];
    }

    // init: slot 0 = inputs for step 0 (x row 0, h[-1]=0); counters 0.
    if (tid < 8) cnts[tid >> 2][tid & 3] = 0;
    if (tid < H_) {
        const int u = tid;
        bufL3[0][(u >> 5) * 36 + (u & 31)] = xin[(long)b * T_ * H_ + u];
        bufL3[0][(2 + (u >> 5)) * 36 + (u & 31)] = 0.f;
    } else if (tid < 128) {
        const int u = tid - 64;
        bufL4[0][(2 + (u >> 5)) * 36 + (u & 31)] = 0.f;
    }
    __syncthreads();

    float c_st = 0.f;
    if (role == 0) {
        unsigned bp = 0;                          // cached L4 progress
        for (int t = 0; t < T_; ++t) {
            // prefetch next x row (kc==1 lanes, one float each) before gating
            float xn = 0.f;
            if (kc == 1 && t + 1 < T_)
                xn = xin[((long)b * T_ + t + 1) * H_ + j];
            wait_ge(cnts[0], (unsigned)t);                   // own h[t-1] + x[t]
            if (t >= 4) {                                    // bufL4[t&3].x reuse
                const unsigned need = (unsigned)(t - 3);
                while (bp < need) bp = min4v(cnts[1]);
            }
            float acc[4];
            dot4x32(&bufL3[t & 3][kc * 36], wt, acc);
            acc[0] = dpp_addf<0xB1>(acc[0]); acc[1] = dpp_addf<0xB1>(acc[1]);
            acc[2] = dpp_addf<0xB1>(acc[2]); acc[3] = dpp_addf<0xB1>(acc[3]);
            acc[0] = dpp_addf<0x4E>(acc[0]); acc[1] = dpp_addf<0x4E>(acc[1]);
            acc[2] = dpp_addf<0x4E>(acc[2]); acc[3] = dpp_addf<0x4E>(acc[3]);
            if (kc == 0) {
                float i_ = fast_sigmoid(acc[0] + bias0);
                float f_ = fast_sigmoid(acc[1] + bias1);
                float g_ = fast_tanh   (acc[2] + bias2);
                float o_ = fast_sigmoid(acc[3] + bias3);
                c_st = f_ * c_st + i_ * g_;
                float h = o_ * fast_tanh(c_st);
                bufL3[(t + 1) & 3][(2 + (j >> 5)) * 36 + (j & 31)] = h; // own h
                bufL4[t & 3][(j >> 5) * 36 + (j & 31)] = h;             // L4 x
            }
            if (kc == 1)
                bufL3[(t + 1) & 3][(j >> 5) * 36 + (j & 31)] = xn;  // next x row
            publish_cnt(&cnts[0][wv], (unsigned)(t + 1), lane0);
        }
    } else {
        unsigned pp = 0;                          // cached L3 progress
        for (int t = 0; t < T_; ++t) {
            wait_ge(cnts[1], (unsigned)t);
            { const unsigned need = (unsigned)(t + 1);       // x = h_L3[t]
              while (pp < need) pp = min4v(cnts[0]); }
            float acc[4];
            dot4x32(&bufL4[t & 3][kc * 36], wt, acc);
            acc[0] = dpp_addf<0xB1>(acc[0]); acc[1] = dpp_addf<0xB1>(acc[1]);
            acc[2] = dpp_addf<0xB1>(acc[2]); acc[3] = dpp_addf<0xB1>(acc[3]);
            acc[0] = dpp_addf<0x4E>(acc[0]); acc[1] = dpp_addf<0x4E>(acc[1]);
            acc[2] = dpp_addf<0x4E>(acc[2]); acc[3] = dpp_addf<0x4E>(acc[3]);
            if (kc == 0) {
                float i_ = fast_sigmoid(acc[0] + bias0);
                float f_ = fast_sigmoid(acc[1] + bias1);
                float g_ = fast_tanh   (acc[2] + bias2);
                float o_ = fast_sigmoid(acc[3] + bias3);
                c_st = f_ * c_st + i_ * g_;
                float h = o_ * fast_tanh(c_st);
                bufL4[(t + 1) & 3][(2 + (j >> 5)) * 36 + (j & 31)] = h; // own h
                hout[((long)b * T_ + t) * H_ + j] = h;
            }
            publish_cnt(&cnts[1][wv], (unsigned)(t + 1), lane0);
        }
    }
}

// MLP head (R3-R15-validated): wave-uniform W1 -> scalar loads. ~25 us.
__global__ __launch_bounds__(256)
void mlp_head_v2(const float* __restrict__ hbuf,
                 const float* __restrict__ W1,
                 const float* __restrict__ b1,
                 const float* __restrict__ W2,
                 const float* __restrict__ b2,
                 float* __restrict__ out)
{
    const long r = (long)blockIdx.x * 256 + threadIdx.x;

    float row[H_];
    const float4* src = (const float4*)(hbuf + r * H_);
    #pragma unroll
    for (int q = 0; q < 16; ++q) {
        float4 v = src[q];
        row[4*q+0] = fmaxf(v.x, 0.f); row[4*q+1] = fmaxf(v.y, 0.f);
        row[4*q+2] = fmaxf(v.z, 0.f); row[4*q+3] = fmaxf(v.w, 0.f);
    }
    #pragma unroll
    for (int q = 0; q < 16; ++q)
        asm volatile("" : "+v"(row[4*q]), "+v"(row[4*q+1]),
                         "+v"(row[4*q+2]), "+v"(row[4*q+3]));

    float acc = b2[0];
    for (int jj = 0; jj < H_; ++jj) {
        const float* wrow = W1 + jj * H_;
        float s0 = 0.f, s1 = 0.f, s2 = 0.f, s3 = 0.f;
        #pragma unroll
        for (int q = 0; q < 16; ++q) {
            s0 += row[4*q+0] * wrow[4*q+0];
            s1 += row[4*q+1] * wrow[4*q+1];
            s2 += row[4*q+2] * wrow[4*q+2];
            s3 += row[4*q+3] * wrow[4*q+3];
        }
        float y = fmaxf(b1[jj] + (s0 + s1) + (s2 + s3), 0.f);
        acc += y * W2[jj];
    }
    out[r] = acc;
}

extern "C" void kernel_launch(void* const* d_in, const int* in_sizes, int n_in,
                              void* d_out, int out_size, void* d_ws, size_t ws_size,
                              hipStream_t stream) {
    const float* x     = (const float*)d_in[0];   // [B,T,1]
    const float* w_ih0 = (const float*)d_in[1];   // [256]
    const float* w_ihr = (const float*)d_in[2];   // [4,256,64]
    const float* w_hh  = (const float*)d_in[3];   // [5,256,64]
    const float* b_ih  = (const float*)d_in[4];   // [5,256]
    const float* b_hh  = (const float*)d_in[5];   // [5,256]
    const float* W1    = (const float*)d_in[6];   // [64,64]
    const float* b1    = (const float*)d_in[7];   // [64]
    const float* W2    = (const float*)d_in[8];   // [64]
    const float* b2    = (const float*)d_in[9];   // [1]
    // d_in[10] = future (0)

    float* out = (float*)d_out;
    float* buf = (float*)d_ws;                    // [B,T,64] fp32 = 64 MB

    const long LW = 4L * H_ * H_;   // 16384 floats per layer weight block
    const long LB = 4L * H_;        // 256 floats per layer bias block

    // K1'': [L0+L1+L2] decoupled triple -> buf = h_L2
    lstm_tri012<<<dim3(B_), dim3(768), 0, stream>>>(
        x, buf,
        w_ih0, w_hh + 0 * LW, b_ih + 0 * LB, b_hh + 0 * LB,
        w_ihr + 0 * LW, w_hh + 1 * LW, b_ih + 1 * LB, b_hh + 1 * LB,
        w_ihr + 1 * LW, w_hh + 2 * LW, b_ih + 2 * LB, b_hh + 2 * LB);

    // K2'': [L3+L4] decoupled pair, in-place on buf -> buf = h_L4
    lstm_pair34<<<dim3(B_), dim3(512), 0, stream>>>(
        buf, buf,
        w_ihr + 2 * LW, w_hh + 3 * LW, b_ih + 3 * LB, b_hh + 3 * LB,
        w_ihr + 3 * LW, w_hh + 4 * LW, b_ih + 4 * LB, b_hh + 4 * LB);

    mlp_head_v2<<<dim3((B_ * T_) / 256), dim3(256), 0, stream>>>(
        buf, W1, b1, W2, b2, out);
}

// Round 2
// 1800.278 us; speedup vs baseline: 1.7651x; 1.7651x over previous
//
#include <hip/hip_runtime.h>

#define B_ 256
#define T_ 1024
#define H_ 64

typedef float f32x2 __attribute__((ext_vector_type(2)));
typedef float f32x4 __attribute__((ext_vector_type(4)));

// fast sigmoid/tanh via v_exp_f32 + v_rcp_f32 (validated R2-R15: absmax 0.0)
__device__ __forceinline__ float fast_sigmoid(float x) {
    float e = __builtin_amdgcn_exp2f(-1.4426950408889634f * x);
    return __builtin_amdgcn_rcpf(1.0f + e);
}
__device__ __forceinline__ float fast_tanh(float x) {
    float e = __builtin_amdgcn_exp2f(2.8853900817779268f * x);
    return 1.0f - 2.0f * __builtin_amdgcn_rcpf(1.0f + e);
}

// butterfly add via DPP: 0xB1=xor1, 0x4E=xor2 (NCH=4 -> 2 stages, R8-validated)
template<int CTRL>
__device__ __forceinline__ float dpp_addf(float v) {
    int vi = __builtin_bit_cast(int, v);
    int sh = __builtin_amdgcn_update_dpp(0, vi, CTRL, 0xF, 0xF, true);
    return v + __builtin_bit_cast(float, sh);
}

// R8-validated: barrier draining LDS only (no vmcnt drain).
__device__ __forceinline__ void block_sync_lds() {
    asm volatile("s_waitcnt lgkmcnt(0)\n\ts_barrier" ::: "memory");
}

// packed-FP32 FMA (VOP3P): d.lo = fma(a.lo,b.lo,c.lo), d.hi = fma(a.hi,b.hi,c.hi).
// R2 hypothesis: compiler emits scalar v_fma_f32 for f32x4 FMA; this forces 2/issue.
__device__ __forceinline__ f32x2 pk_fma(f32x2 a, f32x2 b, f32x2 c) {
    f32x2 d;
    asm("v_pk_fma_f32 %0, %1, %2, %3" : "=v"(d) : "v"(a), "v"(b), "v"(c));
    return d;
}

// ---- heavy role building blocks (R8/R12-validated geometry) ----
// thread = (j in [0,64), kc in [0,4)): 4 gate rows {r*64+j} x 32-float chunk
// of [x(0..63) | h(64..127)]; chunk kc at kc*36 floats (conflict-free b128).
// Weights held as f32x2 pairs so the dot runs on v_pk_fma_f32.
__device__ __forceinline__ void load_w_heavy(const float* __restrict__ w_ih,
                                             const float* __restrict__ w_hh,
                                             int j, int kc, f32x2 wt[4][16]) {
    #pragma unroll
    for (int r = 0; r < 4; ++r) {
        const int row = r * H_ + j;
        const float* base = (kc < 2) ? (w_ih + row * H_ + kc * 32)
                                     : (w_hh + row * H_ + (kc - 2) * 32);
        #pragma unroll
        for (int q = 0; q < 8; ++q) {
            f32x4 v = *(const f32x4*)(base + 4 * q);
            f32x2 lo; lo.x = v.x; lo.y = v.y;
            f32x2 hi; hi.x = v.z; hi.y = v.w;
            wt[r][2 * q]     = lo;
            wt[r][2 * q + 1] = hi;
        }
    }
    #pragma unroll
    for (int r = 0; r < 4; ++r)
        #pragma unroll
        for (int q = 0; q < 16; ++q)
            asm volatile("" : "+v"(wt[r][q]));
}

// Same FMA chains / reduction tree as the scalar version: lo accumulates
// components {x,y}, hi {z,w}; final (X+Y)+(Z+W) — bit-identical result.
__device__ __forceinline__ void dot4x32(const float* chunk, const f32x2 wt[4][16],
                                        float acc[4]) {
    const f32x4* xv = (const f32x4*)chunk;
    f32x2 lo0 = {0,0}, lo1 = {0,0}, lo2 = {0,0}, lo3 = {0,0};
    f32x2 hi0 = {0,0}, hi1 = {0,0}, hi2 = {0,0}, hi3 = {0,0};
    #pragma unroll
    for (int q = 0; q < 8; ++q) {
        f32x4 h4 = xv[q];
        f32x2 hlo; hlo.x = h4.x; hlo.y = h4.y;
        f32x2 hhi; hhi.x = h4.z; hhi.y = h4.w;
        lo0 = pk_fma(wt[0][2*q],   hlo, lo0);
        lo1 = pk_fma(wt[1][2*q],   hlo, lo1);
        lo2 = pk_fma(wt[2][2*q],   hlo, lo2);
        lo3 = pk_fma(wt[3][2*q],   hlo, lo3);
        hi0 = pk_fma(wt[0][2*q+1], hhi, hi0);
        hi1 = pk_fma(wt[1][2*q+1], hhi, hi1);
        hi2 = pk_fma(wt[2][2*q+1], hhi, hi2);
        hi3 = pk_fma(wt[3][2*q+1], hhi, hi3);
    }
    acc[0] = (lo0.x + lo0.y) + (hi0.x + hi0.y);
    acc[1] = (lo1.x + lo1.y) + (hi1.x + hi1.y);
    acc[2] = (lo2.x + lo2.y) + (hi2.x + hi2.y);
    acc[3] = (lo3.x + lo3.y) + (hi3.x + hi3.y);
}

// ---------------------------------------------------------------------------
// K1': diagonal TRIPLE [L0+L1+L2]. role 0 = L0 (light: h-only 16-float
// chunks, scalar-x term), roles 1,2 = heavy. L0 t=s, L1 t=s-1, L2 t=s-2.
// h flows role->role through LDS; L2 writes global h_L2.  (R12 structure)
// ---------------------------------------------------------------------------
__global__ __attribute__((amdgpu_flat_work_group_size(768, 768)))
void lstm_tri012(const float* __restrict__ x,      // [B,T]
                 float* __restrict__ hout,         // [B,T,64] = h_L2
                 const float* __restrict__ w_ih0,  // [256]
                 const float* __restrict__ whh0,
                 const float* __restrict__ bih0, const float* __restrict__ bhh0,
                 const float* __restrict__ wih1, const float* __restrict__ whh1,
                 const float* __restrict__ bih1, const float* __restrict__ bhh1,
                 const float* __restrict__ wih2, const float* __restrict__ whh2,
                 const float* __restrict__ bih2, const float* __restrict__ bhh2)
{
    const int b    = blockIdx.x;
    const int tid  = threadIdx.x;
    const int role = tid >> 8;      // 0=L0, 1=L1, 2=L2 (wave-uniform)
    const int loc  = tid & 255;
    const int kc   = loc & 3;
    const int j    = loc >> 2;      // hidden unit

    __shared__ __align__(16) float bufL0[2][80];    // L0 h: 4 chunks x 20
    __shared__ __align__(16) float bufL1[2][144];   // [x|h]: 4 chunks x 36
    __shared__ __align__(16) float bufL2[2][144];

    f32x2 wt[4][16];                // L0 uses [4][8] portion
    float bias0 = 0.f, bias1 = 0.f, bias2 = 0.f, bias3 = 0.f;
    float w00 = 0.f, w01 = 0.f, w02 = 0.f, w03 = 0.f;

    if (role == 0) {
        #pragma unroll
        for (int r = 0; r < 4; ++r) {
            const int row = r * H_ + j;
            const float* base = whh0 + row * H_ + kc * 16;
            #pragma unroll
            for (int q = 0; q < 4; ++q) {
                f32x4 v = *(const f32x4*)(base + 4 * q);
                f32x2 lo; lo.x = v.x; lo.y = v.y;
                f32x2 hi; hi.x = v.z; hi.y = v.w;
                wt[r][2 * q]     = lo;
                wt[r][2 * q + 1] = hi;
            }
        }
        #pragma unroll
        for (int r = 0; r < 4; ++r)
            #pragma unroll
            for (int q = 0; q < 8; ++q)
                asm volatile("" : "+v"(wt[r][q]));
        if (kc == 0) {
            bias0 = bih0[0*H_+j] + bhh0[0*H_+j];
            bias1 = bih0[1*H_+j] + bhh0[1*H_+j];
            bias2 = bih0[2*H_+j] + bhh0[2*H_+j];
            bias3 = bih0[3*H_+j] + bhh0[3*H_+j];
            w00 = w_ih0[0*H_+j]; w01 = w_ih0[1*H_+j];
            w02 = w_ih0[2*H_+j]; w03 = w_ih0[3*H_+j];
        }
    } else {
        const float* wih = (role == 1) ? wih1 : wih2;
        const float* whh = (role == 1) ? whh1 : whh2;
        const float* bih = (role == 1) ? bih1 : bih2;
        const float* bhh = (role == 1) ? bhh1 : bhh2;
        load_w_heavy(wih, whh, j, kc, wt);
        if (kc == 0) {
            bias0 = bih[0*H_+j] + bhh[0*H_+j];
            bias1 = bih[1*H_+j] + bhh[1*H_+j];
            bias2 = bih[2*H_+j] + bhh[2*H_+j];
            bias3 = bih[3*H_+j] + bhh[3*H_+j];
        }
    }
    float c_st = 0.f;
    float xt = (role == 0) ? x[(long)b * T_] : 0.f;

    float (*myBuf)[144] = (role == 1) ? bufL1 : bufL2;

    // LDS init: L0 reads parity 0 at s=0; L1 parity 1 at s=1; L2 parity 0 at s=2.
    if (loc < H_) {
        const int u = loc;
        if (role == 0)      bufL0[0][(u >> 4) * 20 + (u & 15)] = 0.f;         // h_L0[-1]
        else if (role == 1) bufL1[1][(2 + (u >> 5)) * 36 + (u & 31)] = 0.f;   // h_L1[-1]
        else                bufL2[0][(2 + (u >> 5)) * 36 + (u & 31)] = 0.f;   // h_L2[-1]
    }
    block_sync_lds();

    for (int s = 0; s <= T_ + 1; ++s) {
        const int rb = s & 1, wb = rb ^ 1;
        const bool active = (role == 0) ? (s < T_)
                          : (role == 1) ? (s >= 1 && s <= T_)
                                        : (s >= 2);
        if (active) {
            if (role == 0) {
                float xn = 0.f;
                if (s + 1 < T_) xn = x[(long)b * T_ + s + 1];   // wave-uniform
                const f32x4* xv = (const f32x4*)&bufL0[rb][kc * 20];
                f32x2 lo0 = {0,0}, lo1 = {0,0}, lo2 = {0,0}, lo3 = {0,0};
                f32x2 hi0 = {0,0}, hi1 = {0,0}, hi2 = {0,0}, hi3 = {0,0};
                #pragma unroll
                for (int q = 0; q < 4; ++q) {
                    f32x4 h4 = xv[q];
                    f32x2 hlo; hlo.x = h4.x; hlo.y = h4.y;
                    f32x2 hhi; hhi.x = h4.z; hhi.y = h4.w;
                    lo0 = pk_fma(wt[0][2*q],   hlo, lo0);
                    lo1 = pk_fma(wt[1][2*q],   hlo, lo1);
                    lo2 = pk_fma(wt[2][2*q],   hlo, lo2);
                    lo3 = pk_fma(wt[3][2*q],   hlo, lo3);
                    hi0 = pk_fma(wt[0][2*q+1], hhi, hi0);
                    hi1 = pk_fma(wt[1][2*q+1], hhi, hi1);
                    hi2 = pk_fma(wt[2][2*q+1], hhi, hi2);
                    hi3 = pk_fma(wt[3][2*q+1], hhi, hi3);
                }
                float acc0 = (lo0.x + lo0.y) + (hi0.x + hi0.y);
                float acc1 = (lo1.x + lo1.y) + (hi1.x + hi1.y);
                float acc2 = (lo2.x + lo2.y) + (hi2.x + hi2.y);
                float acc3 = (lo3.x + lo3.y) + (hi3.x + hi3.y);
                acc0 = dpp_addf<0xB1>(acc0); acc1 = dpp_addf<0xB1>(acc1);
                acc2 = dpp_addf<0xB1>(acc2); acc3 = dpp_addf<0xB1>(acc3);
                acc0 = dpp_addf<0x4E>(acc0); acc1 = dpp_addf<0x4E>(acc1);
                acc2 = dpp_addf<0x4E>(acc2); acc3 = dpp_addf<0x4E>(acc3);
                if (kc == 0) {
                    float i_ = fast_sigmoid(acc0 + bias0 + w00 * xt);
                    float f_ = fast_sigmoid(acc1 + bias1 + w01 * xt);
                    float g_ = fast_tanh   (acc2 + bias2 + w02 * xt);
                    float o_ = fast_sigmoid(acc3 + bias3 + w03 * xt);
                    c_st = f_ * c_st + i_ * g_;
                    float h = o_ * fast_tanh(c_st);
                    bufL0[wb][(j >> 4) * 20 + (j & 15)] = h;            // own h
                    bufL1[wb][(j >> 5) * 36 + (j & 31)] = h;            // L1's x
                }
                xt = xn;
            } else {
                float acc[4];
                dot4x32(&myBuf[rb][kc * 36], wt, acc);
                acc[0] = dpp_addf<0xB1>(acc[0]); acc[1] = dpp_addf<0xB1>(acc[1]);
                acc[2] = dpp_addf<0xB1>(acc[2]); acc[3] = dpp_addf<0xB1>(acc[3]);
                acc[0] = dpp_addf<0x4E>(acc[0]); acc[1] = dpp_addf<0x4E>(acc[1]);
                acc[2] = dpp_addf<0x4E>(acc[2]); acc[3] = dpp_addf<0x4E>(acc[3]);
                if (kc == 0) {
                    float i_ = fast_sigmoid(acc[0] + bias0);
                    float f_ = fast_sigmoid(acc[1] + bias1);
                    float g_ = fast_tanh   (acc[2] + bias2);
                    float o_ = fast_sigmoid(acc[3] + bias3);
                    c_st = f_ * c_st + i_ * g_;
                    float h = o_ * fast_tanh(c_st);
                    myBuf[wb][(2 + (j >> 5)) * 36 + (j & 31)] = h;      // own h
                    if (role == 1)
                        bufL2[wb][(j >> 5) * 36 + (j & 31)] = h;        // L2's x
                    else
                        hout[((long)b * T_ + (s - 2)) * H_ + j] = h;
                }
            }
        }
        block_sync_lds();
    }
}

// ---------------------------------------------------------------------------
// K2': diagonal PAIR [L3+L4], both heavy roles. L3 t=s (x = h_L2 from global,
// prefetched), L4 t=s-1 (x = h_L3 via LDS). In-place on buf: L3 reads row s+1
// at step s, L4 overwrites row s-1 at step s -> 2-round gap.  (R12 structure)
// ---------------------------------------------------------------------------
__global__ __attribute__((amdgpu_flat_work_group_size(512, 512)))
void lstm_pair34(const float* __restrict__ xin,   // [B,T,64] h_L2 (aliases hout)
                 float* __restrict__ hout,        // [B,T,64] h_L4
                 const float* __restrict__ wih3, const float* __restrict__ whh3,
                 const float* __restrict__ bih3, const float* __restrict__ bhh3,
                 const float* __restrict__ wih4, const float* __restrict__ whh4,
                 const float* __restrict__ bih4, const float* __restrict__ bhh4)
{
    const int b    = blockIdx.x;
    const int tid  = threadIdx.x;
    const int role = tid >> 8;      // 0=L3, 1=L4 (wave-uniform)
    const int loc  = tid & 255;
    const int kc   = loc & 3;
    const int j    = loc >> 2;

    __shared__ __align__(16) float bufL3[2][144];
    __shared__ __align__(16) float bufL4[2][144];

    const float* wih = (role == 0) ? wih3 : wih4;
    const float* whh = (role == 0) ? whh3 : whh4;
    const float* bih = (role == 0) ? bih3 : bih4;
    const float* bhh = (role == 0) ? bhh3 : bhh4;
    float (*myBuf)[144] = (role == 0) ? bufL3 : bufL4;

    f32x2 wt[4][16];
    load_w_heavy(wih, whh, j, kc, wt);

    float bias0 = 0.f, bias1 = 0.f, bias2 = 0.f, bias3 = 0.f;
    if (kc == 0) {
        bias0 = bih[0*H_+j] + bhh[0*H_+j];
        bias1 = bih[1*H_+j] + bhh[1*H_+j];
        bias2 = bih[2*H_+j] + bhh[2*H_+j];
        bias3 = bih[3*H_+j] + bhh[3*H_+j];
    }
    float c_st = 0.f;

    // LDS init: L3 reads parity 0 at s=0 (x row 0 + h=0); L4 parity 1 at s=1.
    if (tid < H_) {
        const int u = tid;
        bufL3[0][(u >> 5) * 36 + (u & 31)] = xin[(long)b * T_ * H_ + u];
        bufL3[0][(2 + (u >> 5)) * 36 + (u & 31)] = 0.f;
    } else if (tid < 128) {
        const int u = tid - 64;
        bufL4[1][(2 + (u >> 5)) * 36 + (u & 31)] = 0.f;
    }
    block_sync_lds();

    for (int s = 0; s <= T_; ++s) {
        const int rb = s & 1, wb = rb ^ 1;
        const bool active = (role == 0) ? (s < T_) : (s >= 1);
        if (active) {
            // L3: prefetch next x row (kc==1 lanes, one float each)
            float xn = 0.f;
            if (role == 0 && kc == 1 && s + 1 < T_)
                xn = xin[((long)b * T_ + s + 1) * H_ + j];

            float acc[4];
            dot4x32(&myBuf[rb][kc * 36], wt, acc);
            acc[0] = dpp_addf<0xB1>(acc[0]); acc[1] = dpp_addf<0xB1>(acc[1]);
            acc[2] = dpp_addf<0xB1>(acc[2]); acc[3] = dpp_addf<0xB1>(acc[3]);
            acc[0] = dpp_addf<0x4E>(acc[0]); acc[1] = dpp_addf<0x4E>(acc[1]);
            acc[2] = dpp_addf<0x4E>(acc[2]); acc[3] = dpp_addf<0x4E>(acc[3]);

            if (kc == 0) {
                float i_ = fast_sigmoid(acc[0] + bias0);
                float f_ = fast_sigmoid(acc[1] + bias1);
                float g_ = fast_tanh   (acc[2] + bias2);
                float o_ = fast_sigmoid(acc[3] + bias3);
                c_st = f_ * c_st + i_ * g_;
                float h = o_ * fast_tanh(c_st);
                myBuf[wb][(2 + (j >> 5)) * 36 + (j & 31)] = h;          // own h
                if (role == 0)
                    bufL4[wb][(j >> 5) * 36 + (j & 31)] = h;            // L4's x
                else
                    hout[((long)b * T_ + (s - 1)) * H_ + j] = h;
            }
            if (role == 0 && kc == 1)
                bufL3[wb][(j >> 5) * 36 + (j & 31)] = xn;               // next x row
        }
        block_sync_lds();
    }
}

// MLP head (R3-R15-validated): wave-uniform W1 -> scalar loads. ~25 us.
__global__ __launch_bounds__(256)
void mlp_head_v2(const float* __restrict__ hbuf,
                 const float* __restrict__ W1,
                 const float* __restrict__ b1,
                 const float* __restrict__ W2,
                 const float* __restrict__ b2,
                 float* __restrict__ out)
{
    const long r = (long)blockIdx.x * 256 + threadIdx.x;

    float row[H_];
    const float4* src = (const float4*)(hbuf + r * H_);
    #pragma unroll
    for (int q = 0; q < 16; ++q) {
        float4 v = src[q];
        row[4*q+0] = fmaxf(v.x, 0.f); row[4*q+1] = fmaxf(v.y, 0.f);
        row[4*q+2] = fmaxf(v.z, 0.f); row[4*q+3] = fmaxf(v.w, 0.f);
    }
    #pragma unroll
    for (int q = 0; q < 16; ++q)
        asm volatile("" : "+v"(row[4*q]), "+v"(row[4*q+1]),
                         "+v"(row[4*q+2]), "+v"(row[4*q+3]));

    float acc = b2[0];
    for (int jj = 0; jj < H_; ++jj) {
        const float* wrow = W1 + jj * H_;
        float s0 = 0.f, s1 = 0.f, s2 = 0.f, s3 = 0.f;
        #pragma unroll
        for (int q = 0; q < 16; ++q) {
            s0 += row[4*q+0] * wrow[4*q+0];
            s1 += row[4*q+1] * wrow[4*q+1];
            s2 += row[4*q+2] * wrow[4*q+2];
            s3 += row[4*q+3] * wrow[4*q+3];
        }
        float y = fmaxf(b1[jj] + (s0 + s1) + (s2 + s3), 0.f);
        acc += y * W2[jj];
    }
    out[r] = acc;
}

extern "C" void kernel_launch(void* const* d_in, const int* in_sizes, int n_in,
                              void* d_out, int out_size, void* d_ws, size_t ws_size,
                              hipStream_t stream) {
    const float* x     = (const float*)d_in[0];   // [B,T,1]
    const float* w_ih0 = (const float*)d_in[1];   // [256]
    const float* w_ihr = (const float*)d_in[2];   // [4,256,64]
    const float* w_hh  = (const float*)d_in[3];   // [5,256,64]
    const float* b_ih  = (const float*)d_in[4];   // [5,256]
    const float* b_hh  = (const float*)d_in[5];   // [5,256]
    const float* W1    = (const float*)d_in[6];   // [64,64]
    const float* b1    = (const float*)d_in[7];   // [64]
    const float* W2    = (const float*)d_in[8];   // [64]
    const float* b2    = (const float*)d_in[9];   // [1]
    // d_in[10] = future (0)

    float* out = (float*)d_out;
    float* buf = (float*)d_ws;                    // [B,T,64] fp32 = 64 MB

    const long LW = 4L * H_ * H_;   // 16384 floats per layer weight block
    const long LB = 4L * H_;        // 256 floats per layer bias block

    // K1': [L0+L1+L2] diagonal triple -> buf = h_L2
    lstm_tri012<<<dim3(B_), dim3(768), 0, stream>>>(
        x, buf,
        w_ih0, w_hh + 0 * LW, b_ih + 0 * LB, b_hh + 0 * LB,
        w_ihr + 0 * LW, w_hh + 1 * LW, b_ih + 1 * LB, b_hh + 1 * LB,
        w_ihr + 1 * LW, w_hh + 2 * LW, b_ih + 2 * LB, b_hh + 2 * LB);

    // K2': [L3+L4] diagonal pair, in-place on buf -> buf = h_L4
    lstm_pair34<<<dim3(B_), dim3(512), 0, stream>>>(
        buf, buf,
        w_ihr + 2 * LW, w_hh + 3 * LW, b_ih + 3 * LB, b_hh + 3 * LB,
        w_ihr + 3 * LW, w_hh + 4 * LW, b_ih + 4 * LB, b_hh + 4 * LB);

    mlp_head_v2<<<dim3((B_ * T_) / 256), dim3(256), 0, stream>>>(
        buf, W1, b1, W2, b2, out);
}

// Round 3
// 1719.778 us; speedup vs baseline: 1.8478x; 1.0468x over previous
//
#include <hip/hip_runtime.h>

#define B_ 256
#define T_ 1024
#define H_ 64

typedef float f32x2 __attribute__((ext_vector_type(2)));
typedef float f32x4 __attribute__((ext_vector_type(4)));

// fast sigmoid/tanh via v_exp_f32 + v_rcp_f32 (validated R2-R15: absmax 0.0)
__device__ __forceinline__ float fast_sigmoid(float x) {
    float e = __builtin_amdgcn_exp2f(-1.4426950408889634f * x);
    return __builtin_amdgcn_rcpf(1.0f + e);
}
__device__ __forceinline__ float fast_tanh(float x) {
    float e = __builtin_amdgcn_exp2f(2.8853900817779268f * x);
    return 1.0f - 2.0f * __builtin_amdgcn_rcpf(1.0f + e);
}

// butterfly add via DPP: 0xB1=xor1, 0x4E=xor2 (NCH=4 -> 2 stages, R8-validated)
template<int CTRL>
__device__ __forceinline__ float dpp_addf(float v) {
    int vi = __builtin_bit_cast(int, v);
    int sh = __builtin_amdgcn_update_dpp(0, vi, CTRL, 0xF, 0xF, true);
    return v + __builtin_bit_cast(float, sh);
}

// R8-validated: barrier draining LDS only (no vmcnt drain).
__device__ __forceinline__ void block_sync_lds() {
    asm volatile("s_waitcnt lgkmcnt(0)\n\ts_barrier" ::: "memory");
}

__device__ __forceinline__ float hsum4(f32x4 v) { return (v.x + v.y) + (v.z + v.w); }

// ---- heavy role building blocks (R8/R12-validated geometry) ----
// thread = (j in [0,64), kc in [0,4)): 4 gate rows {r*64+j} x 32-float chunk
// of [x(0..63) | h(64..127)]; chunk kc at kc*36 floats (conflict-free b128).
__device__ __forceinline__ void load_w_heavy(const float* __restrict__ w_ih,
                                             const float* __restrict__ w_hh,
                                             int j, int kc, f32x4 wt[4][8]) {
    #pragma unroll
    for (int r = 0; r < 4; ++r) {
        const int row = r * H_ + j;
        const float* base = (kc < 2) ? (w_ih + row * H_ + kc * 32)
                                     : (w_hh + row * H_ + (kc - 2) * 32);
        #pragma unroll
        for (int q = 0; q < 8; ++q)
            wt[r][q] = *(const f32x4*)(base + 4 * q);
    }
    #pragma unroll
    for (int r = 0; r < 4; ++r)
        #pragma unroll
        for (int q = 0; q < 8; ++q)
            asm volatile("" : "+v"(wt[r][q]));
}

__device__ __forceinline__ void dot4x32(const float* chunk, const f32x4 wt[4][8],
                                        float acc[4]) {
    const f32x4* xv = (const f32x4*)chunk;
    f32x4 a0 = {0,0,0,0}, a1 = {0,0,0,0}, a2 = {0,0,0,0}, a3 = {0,0,0,0};
    #pragma unroll
    for (int q = 0; q < 8; ++q) {
        f32x4 hq = xv[q];
        a0 = __builtin_elementwise_fma(wt[0][q], hq, a0);
        a1 = __builtin_elementwise_fma(wt[1][q], hq, a1);
        a2 = __builtin_elementwise_fma(wt[2][q], hq, a2);
        a3 = __builtin_elementwise_fma(wt[3][q], hq, a3);
    }
    acc[0] = hsum4(a0); acc[1] = hsum4(a1);
    acc[2] = hsum4(a2); acc[3] = hsum4(a3);
}

// ---------------------------------------------------------------------------
// K1': diagonal TRIPLE [L0+L1+L2]. role 0 = L0 (light: h-only 16-float
// chunks, scalar-x term), roles 1,2 = heavy. L0 t=s, L1 t=s-1, L2 t=s-2.
// h flows role->role through LDS; L2 writes global h_L2.
// R3 change: __launch_bounds__(768,3) -> compiler budgets for 1 block/CU
// (12 waves), VGPR cap 170, so the 128-float weight array stays in arch
// VGPRs instead of AGPR-spill with per-use v_accvgpr_read.
// ---------------------------------------------------------------------------
__global__ __launch_bounds__(768, 3)
void lstm_tri012(const float* __restrict__ x,      // [B,T]
                 float* __restrict__ hout,         // [B,T,64] = h_L2
                 const float* __restrict__ w_ih0,  // [256]
                 const float* __restrict__ whh0,
                 const float* __restrict__ bih0, const float* __restrict__ bhh0,
                 const float* __restrict__ wih1, const float* __restrict__ whh1,
                 const float* __restrict__ bih1, const float* __restrict__ bhh1,
                 const float* __restrict__ wih2, const float* __restrict__ whh2,
                 const float* __restrict__ bih2, const float* __restrict__ bhh2)
{
    const int b    = blockIdx.x;
    const int tid  = threadIdx.x;
    const int role = tid >> 8;      // 0=L0, 1=L1, 2=L2 (wave-uniform)
    const int loc  = tid & 255;
    const int kc   = loc & 3;
    const int j    = loc >> 2;      // hidden unit

    __shared__ __align__(16) float bufL0[2][80];    // L0 h: 4 chunks x 20
    __shared__ __align__(16) float bufL1[2][144];   // [x|h]: 4 chunks x 36
    __shared__ __align__(16) float bufL2[2][144];

    f32x4 wt[4][8];                 // L0 uses [4][4] portion
    float bias0 = 0.f, bias1 = 0.f, bias2 = 0.f, bias3 = 0.f;
    float w00 = 0.f, w01 = 0.f, w02 = 0.f, w03 = 0.f;

    if (role == 0) {
        #pragma unroll
        for (int r = 0; r < 4; ++r) {
            const int row = r * H_ + j;
            const float* base = whh0 + row * H_ + kc * 16;
            #pragma unroll
            for (int q = 0; q < 4; ++q)
                wt[r][q] = *(const f32x4*)(base + 4 * q);
        }
        #pragma unroll
        for (int r = 0; r < 4; ++r)
            #pragma unroll
            for (int q = 0; q < 4; ++q)
                asm volatile("" : "+v"(wt[r][q]));
        if (kc == 0) {
            bias0 = bih0[0*H_+j] + bhh0[0*H_+j];
            bias1 = bih0[1*H_+j] + bhh0[1*H_+j];
            bias2 = bih0[2*H_+j] + bhh0[2*H_+j];
            bias3 = bih0[3*H_+j] + bhh0[3*H_+j];
            w00 = w_ih0[0*H_+j]; w01 = w_ih0[1*H_+j];
            w02 = w_ih0[2*H_+j]; w03 = w_ih0[3*H_+j];
        }
    } else {
        const float* wih = (role == 1) ? wih1 : wih2;
        const float* whh = (role == 1) ? whh1 : whh2;
        const float* bih = (role == 1) ? bih1 : bih2;
        const float* bhh = (role == 1) ? bhh1 : bhh2;
        load_w_heavy(wih, whh, j, kc, wt);
        if (kc == 0) {
            bias0 = bih[0*H_+j] + bhh[0*H_+j];
            bias1 = bih[1*H_+j] + bhh[1*H_+j];
            bias2 = bih[2*H_+j] + bhh[2*H_+j];
            bias3 = bih[3*H_+j] + bhh[3*H_+j];
        }
    }
    float c_st = 0.f;
    float xt = (role == 0) ? x[(long)b * T_] : 0.f;

    float (*myBuf)[144] = (role == 1) ? bufL1 : bufL2;

    // LDS init: L0 reads parity 0 at s=0; L1 parity 1 at s=1; L2 parity 0 at s=2.
    if (loc < H_) {
        const int u = loc;
        if (role == 0)      bufL0[0][(u >> 4) * 20 + (u & 15)] = 0.f;         // h_L0[-1]
        else if (role == 1) bufL1[1][(2 + (u >> 5)) * 36 + (u & 31)] = 0.f;   // h_L1[-1]
        else                bufL2[0][(2 + (u >> 5)) * 36 + (u & 31)] = 0.f;   // h_L2[-1]
    }
    block_sync_lds();

    for (int s = 0; s <= T_ + 1; ++s) {
        const int rb = s & 1, wb = rb ^ 1;
        const bool active = (role == 0) ? (s < T_)
                          : (role == 1) ? (s >= 1 && s <= T_)
                                        : (s >= 2);
        if (active) {
            if (role == 0) {
                float xn = 0.f;
                if (s + 1 < T_) xn = x[(long)b * T_ + s + 1];   // wave-uniform
                const f32x4* xv = (const f32x4*)&bufL0[rb][kc * 20];
                f32x4 h0 = xv[0], h1 = xv[1], h2 = xv[2], h3 = xv[3];
                f32x4 a0 = {0,0,0,0}, a1 = {0,0,0,0}, a2 = {0,0,0,0}, a3 = {0,0,0,0};
                a0 = __builtin_elementwise_fma(wt[0][0], h0, a0);
                a1 = __builtin_elementwise_fma(wt[1][0], h0, a1);
                a2 = __builtin_elementwise_fma(wt[2][0], h0, a2);
                a3 = __builtin_elementwise_fma(wt[3][0], h0, a3);
                a0 = __builtin_elementwise_fma(wt[0][1], h1, a0);
                a1 = __builtin_elementwise_fma(wt[1][1], h1, a1);
                a2 = __builtin_elementwise_fma(wt[2][1], h1, a2);
                a3 = __builtin_elementwise_fma(wt[3][1], h1, a3);
                a0 = __builtin_elementwise_fma(wt[0][2], h2, a0);
                a1 = __builtin_elementwise_fma(wt[1][2], h2, a1);
                a2 = __builtin_elementwise_fma(wt[2][2], h2, a2);
                a3 = __builtin_elementwise_fma(wt[3][2], h2, a3);
                a0 = __builtin_elementwise_fma(wt[0][3], h3, a0);
                a1 = __builtin_elementwise_fma(wt[1][3], h3, a1);
                a2 = __builtin_elementwise_fma(wt[2][3], h3, a2);
                a3 = __builtin_elementwise_fma(wt[3][3], h3, a3);
                float acc0 = hsum4(a0), acc1 = hsum4(a1);
                float acc2 = hsum4(a2), acc3 = hsum4(a3);
                acc0 = dpp_addf<0xB1>(acc0); acc1 = dpp_addf<0xB1>(acc1);
                acc2 = dpp_addf<0xB1>(acc2); acc3 = dpp_addf<0xB1>(acc3);
                acc0 = dpp_addf<0x4E>(acc0); acc1 = dpp_addf<0x4E>(acc1);
                acc2 = dpp_addf<0x4E>(acc2); acc3 = dpp_addf<0x4E>(acc3);
                if (kc == 0) {
                    float i_ = fast_sigmoid(acc0 + bias0 + w00 * xt);
                    float f_ = fast_sigmoid(acc1 + bias1 + w01 * xt);
                    float g_ = fast_tanh   (acc2 + bias2 + w02 * xt);
                    float o_ = fast_sigmoid(acc3 + bias3 + w03 * xt);
                    c_st = f_ * c_st + i_ * g_;
                    float h = o_ * fast_tanh(c_st);
                    bufL0[wb][(j >> 4) * 20 + (j & 15)] = h;            // own h
                    bufL1[wb][(j >> 5) * 36 + (j & 31)] = h;            // L1's x
                }
                xt = xn;
            } else {
                float acc[4];
                dot4x32(&myBuf[rb][kc * 36], wt, acc);
                acc[0] = dpp_addf<0xB1>(acc[0]); acc[1] = dpp_addf<0xB1>(acc[1]);
                acc[2] = dpp_addf<0xB1>(acc[2]); acc[3] = dpp_addf<0xB1>(acc[3]);
                acc[0] = dpp_addf<0x4E>(acc[0]); acc[1] = dpp_addf<0x4E>(acc[1]);
                acc[2] = dpp_addf<0x4E>(acc[2]); acc[3] = dpp_addf<0x4E>(acc[3]);
                if (kc == 0) {
                    float i_ = fast_sigmoid(acc[0] + bias0);
                    float f_ = fast_sigmoid(acc[1] + bias1);
                    float g_ = fast_tanh   (acc[2] + bias2);
                    float o_ = fast_sigmoid(acc[3] + bias3);
                    c_st = f_ * c_st + i_ * g_;
                    float h = o_ * fast_tanh(c_st);
                    myBuf[wb][(2 + (j >> 5)) * 36 + (j & 31)] = h;      // own h
                    if (role == 1)
                        bufL2[wb][(j >> 5) * 36 + (j & 31)] = h;        // L2's x
                    else
                        hout[((long)b * T_ + (s - 2)) * H_ + j] = h;
                }
            }
        }
        block_sync_lds();
    }
}

// ---------------------------------------------------------------------------
// K2': diagonal PAIR [L3+L4], both heavy roles. L3 t=s (x = h_L2 from global,
// prefetched), L4 t=s-1 (x = h_L3 via LDS). In-place on buf: L3 reads row s+1
// at step s, L4 overwrites row s-1 at step s -> 2-round gap.
// R3 change: __launch_bounds__(512,2) -> 1 block/CU budget, VGPR cap 256.
// ---------------------------------------------------------------------------
__global__ __launch_bounds__(512, 2)
void lstm_pair34(const float* __restrict__ xin,   // [B,T,64] h_L2 (aliases hout)
                 float* __restrict__ hout,        // [B,T,64] h_L4
                 const float* __restrict__ wih3, const float* __restrict__ whh3,
                 const float* __restrict__ bih3, const float* __restrict__ bhh3,
                 const float* __restrict__ wih4, const float* __restrict__ whh4,
                 const float* __restrict__ bih4, const float* __restrict__ bhh4)
{
    const int b    = blockIdx.x;
    const int tid  = threadIdx.x;
    const int role = tid >> 8;      // 0=L3, 1=L4 (wave-uniform)
    const int loc  = tid & 255;
    const int kc   = loc & 3;
    const int j    = loc >> 2;

    __shared__ __align__(16) float bufL3[2][144];
    __shared__ __align__(16) float bufL4[2][144];

    const float* wih = (role == 0) ? wih3 : wih4;
    const float* whh = (role == 0) ? whh3 : whh4;
    const float* bih = (role == 0) ? bih3 : bih4;
    const float* bhh = (role == 0) ? bhh3 : bhh4;
    float (*myBuf)[144] = (role == 0) ? bufL3 : bufL4;

    f32x4 wt[4][8];
    load_w_heavy(wih, whh, j, kc, wt);

    float bias0 = 0.f, bias1 = 0.f, bias2 = 0.f, bias3 = 0.f;
    if (kc == 0) {
        bias0 = bih[0*H_+j] + bhh[0*H_+j];
        bias1 = bih[1*H_+j] + bhh[1*H_+j];
        bias2 = bih[2*H_+j] + bhh[2*H_+j];
        bias3 = bih[3*H_+j] + bhh[3*H_+j];
    }
    float c_st = 0.f;

    // LDS init: L3 reads parity 0 at s=0 (x row 0 + h=0); L4 parity 1 at s=1.
    if (tid < H_) {
        const int u = tid;
        bufL3[0][(u >> 5) * 36 + (u & 31)] = xin[(long)b * T_ * H_ + u];
        bufL3[0][(2 + (u >> 5)) * 36 + (u & 31)] = 0.f;
    } else if (tid < 128) {
        const int u = tid - 64;
        bufL4[1][(2 + (u >> 5)) * 36 + (u & 31)] = 0.f;
    }
    block_sync_lds();

    for (int s = 0; s <= T_; ++s) {
        const int rb = s & 1, wb = rb ^ 1;
        const bool active = (role == 0) ? (s < T_) : (s >= 1);
        if (active) {
            // L3: prefetch next x row (kc==1 lanes, one float each)
            float xn = 0.f;
            if (role == 0 && kc == 1 && s + 1 < T_)
                xn = xin[((long)b * T_ + s + 1) * H_ + j];

            float acc[4];
            dot4x32(&myBuf[rb][kc * 36], wt, acc);
            acc[0] = dpp_addf<0xB1>(acc[0]); acc[1] = dpp_addf<0xB1>(acc[1]);
            acc[2] = dpp_addf<0xB1>(acc[2]); acc[3] = dpp_addf<0xB1>(acc[3]);
            acc[0] = dpp_addf<0x4E>(acc[0]); acc[1] = dpp_addf<0x4E>(acc[1]);
            acc[2] = dpp_addf<0x4E>(acc[2]); acc[3] = dpp_addf<0x4E>(acc[3]);

            if (kc == 0) {
                float i_ = fast_sigmoid(acc[0] + bias0);
                float f_ = fast_sigmoid(acc[1] + bias1);
                float g_ = fast_tanh   (acc[2] + bias2);
                float o_ = fast_sigmoid(acc[3] + bias3);
                c_st = f_ * c_st + i_ * g_;
                float h = o_ * fast_tanh(c_st);
                myBuf[wb][(2 + (j >> 5)) * 36 + (j & 31)] = h;          // own h
                if (role == 0)
                    bufL4[wb][(j >> 5) * 36 + (j & 31)] = h;            // L4's x
                else
                    hout[((long)b * T_ + (s - 1)) * H_ + j] = h;
            }
            if (role == 0 && kc == 1)
                bufL3[wb][(j >> 5) * 36 + (j & 31)] = xn;               // next x row
        }
        block_sync_lds();
    }
}

// MLP head (R3-R15-validated): wave-uniform W1 -> scalar loads. ~25 us.
__global__ __launch_bounds__(256)
void mlp_head_v2(const float* __restrict__ hbuf,
                 const float* __restrict__ W1,
                 const float* __restrict__ b1,
                 const float* __restrict__ W2,
                 const float* __restrict__ b2,
                 float* __restrict__ out)
{
    const long r = (long)blockIdx.x * 256 + threadIdx.x;

    float row[H_];
    const float4* src = (const float4*)(hbuf + r * H_);
    #pragma unroll
    for (int q = 0; q < 16; ++q) {
        float4 v = src[q];
        row[4*q+0] = fmaxf(v.x, 0.f); row[4*q+1] = fmaxf(v.y, 0.f);
        row[4*q+2] = fmaxf(v.z, 0.f); row[4*q+3] = fmaxf(v.w, 0.f);
    }
    #pragma unroll
    for (int q = 0; q < 16; ++q)
        asm volatile("" : "+v"(row[4*q]), "+v"(row[4*q+1]),
                         "+v"(row[4*q+2]), "+v"(row[4*q+3]));

    float acc = b2[0];
    for (int jj = 0; jj < H_; ++jj) {
        const float* wrow = W1 + jj * H_;
        float s0 = 0.f, s1 = 0.f, s2 = 0.f, s3 = 0.f;
        #pragma unroll
        for (int q = 0; q < 16; ++q) {
            s0 += row[4*q+0] * wrow[4*q+0];
            s1 += row[4*q+1] * wrow[4*q+1];
            s2 += row[4*q+2] * wrow[4*q+2];
            s3 += row[4*q+3] * wrow[4*q+3];
        }
        float y = fmaxf(b1[jj] + (s0 + s1) + (s2 + s3), 0.f);
        acc += y * W2[jj];
    }
    out[r] = acc;
}

extern "C" void kernel_launch(void* const* d_in, const int* in_sizes, int n_in,
                              void* d_out, int out_size, void* d_ws, size_t ws_size,
                              hipStream_t stream) {
    const float* x     = (const float*)d_in[0];   // [B,T,1]
    const float* w_ih0 = (const float*)d_in[1];   // [256]
    const float* w_ihr = (const float*)d_in[2];   // [4,256,64]
    const float* w_hh  = (const float*)d_in[3];   // [5,256,64]
    const float* b_ih  = (const float*)d_in[4];   // [5,256]
    const float* b_hh  = (const float*)d_in[5];   // [5,256]
    const float* W1    = (const float*)d_in[6];   // [64,64]
    const float* b1    = (const float*)d_in[7];   // [64]
    const float* W2    = (const float*)d_in[8];   // [64]
    const float* b2    = (const float*)d_in[9];   // [1]
    // d_in[10] = future (0)

    float* out = (float*)d_out;
    float* buf = (float*)d_ws;                    // [B,T,64] fp32 = 64 MB

    const long LW = 4L * H_ * H_;   // 16384 floats per layer weight block
    const long LB = 4L * H_;        // 256 floats per layer bias block

    // K1': [L0+L1+L2] diagonal triple -> buf = h_L2
    lstm_tri012<<<dim3(B_), dim3(768), 0, stream>>>(
        x, buf,
        w_ih0, w_hh + 0 * LW, b_ih + 0 * LB, b_hh + 0 * LB,
        w_ihr + 0 * LW, w_hh + 1 * LW, b_ih + 1 * LB, b_hh + 1 * LB,
        w_ihr + 1 * LW, w_hh + 2 * LW, b_ih + 2 * LB, b_hh + 2 * LB);

    // K2': [L3+L4] diagonal pair, in-place on buf -> buf = h_L4
    lstm_pair34<<<dim3(B_), dim3(512), 0, stream>>>(
        buf, buf,
        w_ihr + 2 * LW, w_hh + 3 * LW, b_ih + 3 * LB, b_hh + 3 * LB,
        w_ihr + 3 * LW, w_hh + 4 * LW, b_ih + 4 * LB, b_hh + 4 * LB);

    mlp_head_v2<<<dim3((B_ * T_) / 256), dim3(256), 0, stream>>>(
        buf, W1, b1, W2, b2, out);
}

// Round 4
// 1542.640 us; speedup vs baseline: 2.0599x; 1.1148x over previous
//
#include <hip/hip_runtime.h>

#define B_ 256
#define T_ 1024
#define H_ 64

typedef float f32x2 __attribute__((ext_vector_type(2)));
typedef float f32x4 __attribute__((ext_vector_type(4)));

// fast tanh via v_exp_f32 + v_rcp_f32 (validated: absmax 0.0)
__device__ __forceinline__ float fast_tanh(float x) {
    float e = __builtin_amdgcn_exp2f(2.8853900817779268f * x);
    return 1.0f - 2.0f * __builtin_amdgcn_rcpf(1.0f + e);
}

// butterfly add via DPP: 0xB1=xor1, 0x4E=xor2 (NCH=4 -> 2 stages, R8-validated)
template<int CTRL>
__device__ __forceinline__ float dpp_addf(float v) {
    int vi = __builtin_bit_cast(int, v);
    int sh = __builtin_amdgcn_update_dpp(0, vi, CTRL, 0xF, 0xF, true);
    return v + __builtin_bit_cast(float, sh);
}
// pure DPP move (gather partner lane's value; bound_ctrl -> 0 for invalid)
template<int CTRL>
__device__ __forceinline__ float dpp_movf(float v) {
    int vi = __builtin_bit_cast(int, v);
    int sh = __builtin_amdgcn_update_dpp(0, vi, CTRL, 0xF, 0xF, true);
    return __builtin_bit_cast(float, sh);
}

// R8-validated: barrier draining LDS only (no vmcnt drain).
__device__ __forceinline__ void block_sync_lds() {
    asm volatile("s_waitcnt lgkmcnt(0)\n\ts_barrier" ::: "memory");
}

__device__ __forceinline__ float hsum4(f32x4 v) { return (v.x + v.y) + (v.z + v.w); }

// ---- R4: shared-trans activation, one gate per kc lane ----
// Preconditions: acc[0..3] are the COMPLETE butterfly-reduced gate sums,
// bitwise-identical on all 4 kc lanes (IEEE add commutativity). Lane kc
// computes act(gate kc) with the shared exp2+rcp form; 3 dpp moves deliver
// f,g,o to the kc==0 lane. Returns act (own gate) and fv/gv/ov via refs.
__device__ __forceinline__ void gate_acts(const float acc[4], float bias_,
                                          float xterm, int kc,
                                          float& act, float& fv, float& gv, float& ov) {
    float acc_lo = (kc & 1) ? acc[1] : acc[0];
    float acc_hi = (kc & 1) ? acc[3] : acc[2];
    float pre = ((kc & 2) ? acc_hi : acc_lo) + bias_ + xterm;
    const bool isg = (kc == 2);
    float kk = isg ? 2.8853900817779268f : -1.4426950408889634f;
    float e = __builtin_amdgcn_exp2f(kk * pre);
    float r = __builtin_amdgcn_rcpf(1.0f + e);
    act = isg ? 1.0f - 2.0f * r : r;
    fv = dpp_movf<0xB1>(act);       // kc0 <- kc1 (f)
    gv = dpp_movf<0x4E>(act);       // kc0 <- kc2 (g)
    ov = dpp_movf<0x4E>(fv);        // kc0 <- kc2's fv = kc3's act (o)
}

// ---- heavy role building blocks (R8/R12-validated geometry) ----
// thread = (j in [0,64), kc in [0,4)): 4 gate rows {r*64+j} x 32-float chunk
// of [x(0..63) | h(64..127)]; chunk kc at kc*36 floats (conflict-free b128).
__device__ __forceinline__ void load_w_heavy(const float* __restrict__ w_ih,
                                             const float* __restrict__ w_hh,
                                             int j, int kc, f32x4 wt[4][8]) {
    #pragma unroll
    for (int r = 0; r < 4; ++r) {
        const int row = r * H_ + j;
        const float* base = (kc < 2) ? (w_ih + row * H_ + kc * 32)
                                     : (w_hh + row * H_ + (kc - 2) * 32);
        #pragma unroll
        for (int q = 0; q < 8; ++q)
            wt[r][q] = *(const f32x4*)(base + 4 * q);
    }
    #pragma unroll
    for (int r = 0; r < 4; ++r)
        #pragma unroll
        for (int q = 0; q < 8; ++q)
            asm volatile("" : "+v"(wt[r][q]));
}

__device__ __forceinline__ void dot4x32(const float* chunk, const f32x4 wt[4][8],
                                        float acc[4]) {
    const f32x4* xv = (const f32x4*)chunk;
    f32x4 a0 = {0,0,0,0}, a1 = {0,0,0,0}, a2 = {0,0,0,0}, a3 = {0,0,0,0};
    #pragma unroll
    for (int q = 0; q < 8; ++q) {
        f32x4 hq = xv[q];
        a0 = __builtin_elementwise_fma(wt[0][q], hq, a0);
        a1 = __builtin_elementwise_fma(wt[1][q], hq, a1);
        a2 = __builtin_elementwise_fma(wt[2][q], hq, a2);
        a3 = __builtin_elementwise_fma(wt[3][q], hq, a3);
    }
    acc[0] = hsum4(a0); acc[1] = hsum4(a1);
    acc[2] = hsum4(a2); acc[3] = hsum4(a3);
}

// ---------------------------------------------------------------------------
// K1': diagonal TRIPLE [L0+L1+L2]. role 0 = L0 (light: h-only 16-float
// chunks, scalar-x term), roles 1,2 = heavy. L0 t=s, L1 t=s-1, L2 t=s-2.
// h flows role->role through LDS; L2 writes global h_L2.
// R4: shared-trans gate activations (10 -> 4 trans per wave-step).
// ---------------------------------------------------------------------------
__global__ __launch_bounds__(768, 3)
void lstm_tri012(const float* __restrict__ x,      // [B,T]
                 float* __restrict__ hout,         // [B,T,64] = h_L2
                 const float* __restrict__ w_ih0,  // [256]
                 const float* __restrict__ whh0,
                 const float* __restrict__ bih0, const float* __restrict__ bhh0,
                 const float* __restrict__ wih1, const float* __restrict__ whh1,
                 const float* __restrict__ bih1, const float* __restrict__ bhh1,
                 const float* __restrict__ wih2, const float* __restrict__ whh2,
                 const float* __restrict__ bih2, const float* __restrict__ bhh2)
{
    const int b    = blockIdx.x;
    const int tid  = threadIdx.x;
    const int role = tid >> 8;      // 0=L0, 1=L1, 2=L2 (wave-uniform)
    const int loc  = tid & 255;
    const int kc   = loc & 3;
    const int j    = loc >> 2;      // hidden unit

    __shared__ __align__(16) float bufL0[2][80];    // L0 h: 4 chunks x 20
    __shared__ __align__(16) float bufL1[2][144];   // [x|h]: 4 chunks x 36
    __shared__ __align__(16) float bufL2[2][144];

    f32x4 wt[4][8];                 // L0 uses [4][4] portion
    float bias_ = 0.f;              // per-lane: bias of gate kc, unit j
    float w0_   = 0.f;              // L0 only: x-weight of gate kc, unit j

    if (role == 0) {
        #pragma unroll
        for (int r = 0; r < 4; ++r) {
            const int row = r * H_ + j;
            const float* base = whh0 + row * H_ + kc * 16;
            #pragma unroll
            for (int q = 0; q < 4; ++q)
                wt[r][q] = *(const f32x4*)(base + 4 * q);
        }
        #pragma unroll
        for (int r = 0; r < 4; ++r)
            #pragma unroll
            for (int q = 0; q < 4; ++q)
                asm volatile("" : "+v"(wt[r][q]));
        bias_ = bih0[kc*H_+j] + bhh0[kc*H_+j];
        w0_   = w_ih0[kc*H_+j];
    } else {
        const float* wih = (role == 1) ? wih1 : wih2;
        const float* whh = (role == 1) ? whh1 : whh2;
        const float* bih = (role == 1) ? bih1 : bih2;
        const float* bhh = (role == 1) ? bhh1 : bhh2;
        load_w_heavy(wih, whh, j, kc, wt);
        bias_ = bih[kc*H_+j] + bhh[kc*H_+j];
    }
    float c_st = 0.f;
    float xt = (role == 0) ? x[(long)b * T_] : 0.f;

    float (*myBuf)[144] = (role == 1) ? bufL1 : bufL2;

    // LDS init: L0 reads parity 0 at s=0; L1 parity 1 at s=1; L2 parity 0 at s=2.
    if (loc < H_) {
        const int u = loc;
        if (role == 0)      bufL0[0][(u >> 4) * 20 + (u & 15)] = 0.f;         // h_L0[-1]
        else if (role == 1) bufL1[1][(2 + (u >> 5)) * 36 + (u & 31)] = 0.f;   // h_L1[-1]
        else                bufL2[0][(2 + (u >> 5)) * 36 + (u & 31)] = 0.f;   // h_L2[-1]
    }
    block_sync_lds();

    #pragma unroll 2
    for (int s = 0; s <= T_ + 1; ++s) {
        const int rb = s & 1, wb = rb ^ 1;
        const bool active = (role == 0) ? (s < T_)
                          : (role == 1) ? (s >= 1 && s <= T_)
                                        : (s >= 2);
        if (active) {
            if (role == 0) {
                float xn = 0.f;
                if (s + 1 < T_) xn = x[(long)b * T_ + s + 1];   // wave-uniform
                const f32x4* xv = (const f32x4*)&bufL0[rb][kc * 20];
                f32x4 h0 = xv[0], h1 = xv[1], h2 = xv[2], h3 = xv[3];
                f32x4 a0 = {0,0,0,0}, a1 = {0,0,0,0}, a2 = {0,0,0,0}, a3 = {0,0,0,0};
                a0 = __builtin_elementwise_fma(wt[0][0], h0, a0);
                a1 = __builtin_elementwise_fma(wt[1][0], h0, a1);
                a2 = __builtin_elementwise_fma(wt[2][0], h0, a2);
                a3 = __builtin_elementwise_fma(wt[3][0], h0, a3);
                a0 = __builtin_elementwise_fma(wt[0][1], h1, a0);
                a1 = __builtin_elementwise_fma(wt[1][1], h1, a1);
                a2 = __builtin_elementwise_fma(wt[2][1], h1, a2);
                a3 = __builtin_elementwise_fma(wt[3][1], h1, a3);
                a0 = __builtin_elementwise_fma(wt[0][2], h2, a0);
                a1 = __builtin_elementwise_fma(wt[1][2], h2, a1);
                a2 = __builtin_elementwise_fma(wt[2][2], h2, a2);
                a3 = __builtin_elementwise_fma(wt[3][2], h2, a3);
                a0 = __builtin_elementwise_fma(wt[0][3], h3, a0);
                a1 = __builtin_elementwise_fma(wt[1][3], h3, a1);
                a2 = __builtin_elementwise_fma(wt[2][3], h3, a2);
                a3 = __builtin_elementwise_fma(wt[3][3], h3, a3);
                float acc[4];
                acc[0] = hsum4(a0); acc[1] = hsum4(a1);
                acc[2] = hsum4(a2); acc[3] = hsum4(a3);
                acc[0] = dpp_addf<0xB1>(acc[0]); acc[1] = dpp_addf<0xB1>(acc[1]);
                acc[2] = dpp_addf<0xB1>(acc[2]); acc[3] = dpp_addf<0xB1>(acc[3]);
                acc[0] = dpp_addf<0x4E>(acc[0]); acc[1] = dpp_addf<0x4E>(acc[1]);
                acc[2] = dpp_addf<0x4E>(acc[2]); acc[3] = dpp_addf<0x4E>(acc[3]);
                float act, fv, gv, ov;
                gate_acts(acc, bias_, w0_ * xt, kc, act, fv, gv, ov);
                if (kc == 0) {
                    c_st = fv * c_st + act * gv;
                    float h = ov * fast_tanh(c_st);
                    bufL0[wb][(j >> 4) * 20 + (j & 15)] = h;            // own h
                    bufL1[wb][(j >> 5) * 36 + (j & 31)] = h;            // L1's x
                }
                xt = xn;
            } else {
                float acc[4];
                dot4x32(&myBuf[rb][kc * 36], wt, acc);
                acc[0] = dpp_addf<0xB1>(acc[0]); acc[1] = dpp_addf<0xB1>(acc[1]);
                acc[2] = dpp_addf<0xB1>(acc[2]); acc[3] = dpp_addf<0xB1>(acc[3]);
                acc[0] = dpp_addf<0x4E>(acc[0]); acc[1] = dpp_addf<0x4E>(acc[1]);
                acc[2] = dpp_addf<0x4E>(acc[2]); acc[3] = dpp_addf<0x4E>(acc[3]);
                float act, fv, gv, ov;
                gate_acts(acc, bias_, 0.f, kc, act, fv, gv, ov);
                if (kc == 0) {
                    c_st = fv * c_st + act * gv;
                    float h = ov * fast_tanh(c_st);
                    myBuf[wb][(2 + (j >> 5)) * 36 + (j & 31)] = h;      // own h
                    if (role == 1)
                        bufL2[wb][(j >> 5) * 36 + (j & 31)] = h;        // L2's x
                    else
                        hout[((long)b * T_ + (s - 2)) * H_ + j] = h;
                }
            }
        }
        block_sync_lds();
    }
}

// ---------------------------------------------------------------------------
// K2': diagonal PAIR [L3+L4], both heavy roles. L3 t=s (x = h_L2 from global,
// prefetched), L4 t=s-1 (x = h_L3 via LDS). In-place on buf: L3 reads row s+1
// at step s, L4 overwrites row s-1 at step s -> 2-round gap.
// R4: shared-trans gate activations.
// ---------------------------------------------------------------------------
__global__ __launch_bounds__(512, 2)
void lstm_pair34(const float* __restrict__ xin,   // [B,T,64] h_L2 (aliases hout)
                 float* __restrict__ hout,        // [B,T,64] h_L4
                 const float* __restrict__ wih3, const float* __restrict__ whh3,
                 const float* __restrict__ bih3, const float* __restrict__ bhh3,
                 const float* __restrict__ wih4, const float* __restrict__ whh4,
                 const float* __restrict__ bih4, const float* __restrict__ bhh4)
{
    const int b    = blockIdx.x;
    const int tid  = threadIdx.x;
    const int role = tid >> 8;      // 0=L3, 1=L4 (wave-uniform)
    const int loc  = tid & 255;
    const int kc   = loc & 3;
    const int j    = loc >> 2;

    __shared__ __align__(16) float bufL3[2][144];
    __shared__ __align__(16) float bufL4[2][144];

    const float* wih = (role == 0) ? wih3 : wih4;
    const float* whh = (role == 0) ? whh3 : whh4;
    const float* bih = (role == 0) ? bih3 : bih4;
    const float* bhh = (role == 0) ? bhh3 : bhh4;
    float (*myBuf)[144] = (role == 0) ? bufL3 : bufL4;

    f32x4 wt[4][8];
    load_w_heavy(wih, whh, j, kc, wt);

    float bias_ = bih[kc*H_+j] + bhh[kc*H_+j];
    float c_st = 0.f;

    // LDS init: L3 reads parity 0 at s=0 (x row 0 + h=0); L4 parity 1 at s=1.
    if (tid < H_) {
        const int u = tid;
        bufL3[0][(u >> 5) * 36 + (u & 31)] = xin[(long)b * T_ * H_ + u];
        bufL3[0][(2 + (u >> 5)) * 36 + (u & 31)] = 0.f;
    } else if (tid < 128) {
        const int u = tid - 64;
        bufL4[1][(2 + (u >> 5)) * 36 + (u & 31)] = 0.f;
    }
    block_sync_lds();

    #pragma unroll 2
    for (int s = 0; s <= T_; ++s) {
        const int rb = s & 1, wb = rb ^ 1;
        const bool active = (role == 0) ? (s < T_) : (s >= 1);
        if (active) {
            // L3: prefetch next x row (kc==1 lanes, one float each)
            float xn = 0.f;
            if (role == 0 && kc == 1 && s + 1 < T_)
                xn = xin[((long)b * T_ + s + 1) * H_ + j];

            float acc[4];
            dot4x32(&myBuf[rb][kc * 36], wt, acc);
            acc[0] = dpp_addf<0xB1>(acc[0]); acc[1] = dpp_addf<0xB1>(acc[1]);
            acc[2] = dpp_addf<0xB1>(acc[2]); acc[3] = dpp_addf<0xB1>(acc[3]);
            acc[0] = dpp_addf<0x4E>(acc[0]); acc[1] = dpp_addf<0x4E>(acc[1]);
            acc[2] = dpp_addf<0x4E>(acc[2]); acc[3] = dpp_addf<0x4E>(acc[3]);

            float act, fv, gv, ov;
            gate_acts(acc, bias_, 0.f, kc, act, fv, gv, ov);
            if (kc == 0) {
                c_st = fv * c_st + act * gv;
                float h = ov * fast_tanh(c_st);
                myBuf[wb][(2 + (j >> 5)) * 36 + (j & 31)] = h;          // own h
                if (role == 0)
                    bufL4[wb][(j >> 5) * 36 + (j & 31)] = h;            // L4's x
                else
                    hout[((long)b * T_ + (s - 1)) * H_ + j] = h;
            }
            if (role == 0 && kc == 1)
                bufL3[wb][(j >> 5) * 36 + (j & 31)] = xn;               // next x row
        }
        block_sync_lds();
    }
}

// MLP head (R3-R15-validated): wave-uniform W1 -> scalar loads. ~25 us.
__global__ __launch_bounds__(256)
void mlp_head_v2(const float* __restrict__ hbuf,
                 const float* __restrict__ W1,
                 const float* __restrict__ b1,
                 const float* __restrict__ W2,
                 const float* __restrict__ b2,
                 float* __restrict__ out)
{
    const long r = (long)blockIdx.x * 256 + threadIdx.x;

    float row[H_];
    const float4* src = (const float4*)(hbuf + r * H_);
    #pragma unroll
    for (int q = 0; q < 16; ++q) {
        float4 v = src[q];
        row[4*q+0] = fmaxf(v.x, 0.f); row[4*q+1] = fmaxf(v.y, 0.f);
        row[4*q+2] = fmaxf(v.z, 0.f); row[4*q+3] = fmaxf(v.w, 0.f);
    }
    #pragma unroll
    for (int q = 0; q < 16; ++q)
        asm volatile("" : "+v"(row[4*q]), "+v"(row[4*q+1]),
                         "+v"(row[4*q+2]), "+v"(row[4*q+3]));

    float acc = b2[0];
    for (int jj = 0; jj < H_; ++jj) {
        const float* wrow = W1 + jj * H_;
        float s0 = 0.f, s1 = 0.f, s2 = 0.f, s3 = 0.f;
        #pragma unroll
        for (int q = 0; q < 16; ++q) {
            s0 += row[4*q+0] * wrow[4*q+0];
            s1 += row[4*q+1] * wrow[4*q+1];
            s2 += row[4*q+2] * wrow[4*q+2];
            s3 += row[4*q+3] * wrow[4*q+3];
        }
        float y = fmaxf(b1[jj] + (s0 + s1) + (s2 + s3), 0.f);
        acc += y * W2[jj];
    }
    out[r] = acc;
}

extern "C" void kernel_launch(void* const* d_in, const int* in_sizes, int n_in,
                              void* d_out, int out_size, void* d_ws, size_t ws_size,
                              hipStream_t stream) {
    const float* x     = (const float*)d_in[0];   // [B,T,1]
    const float* w_ih0 = (const float*)d_in[1];   // [256]
    const float* w_ihr = (const float*)d_in[2];   // [4,256,64]
    const float* w_hh  = (const float*)d_in[3];   // [5,256,64]
    const float* b_ih  = (const float*)d_in[4];   // [5,256]
    const float* b_hh  = (const float*)d_in[5];   // [5,256]
    const float* W1    = (const float*)d_in[6];   // [64,64]
    const float* b1    = (const float*)d_in[7];   // [64]
    const float* W2    = (const float*)d_in[8];   // [64]
    const float* b2    = (const float*)d_in[9];   // [1]
    // d_in[10] = future (0)

    float* out = (float*)d_out;
    float* buf = (float*)d_ws;                    // [B,T,64] fp32 = 64 MB

    const long LW = 4L * H_ * H_;   // 16384 floats per layer weight block
    const long LB = 4L * H_;        // 256 floats per layer bias block

    // K1': [L0+L1+L2] diagonal triple -> buf = h_L2
    lstm_tri012<<<dim3(B_), dim3(768), 0, stream>>>(
        x, buf,
        w_ih0, w_hh + 0 * LW, b_ih + 0 * LB, b_hh + 0 * LB,
        w_ihr + 0 * LW, w_hh + 1 * LW, b_ih + 1 * LB, b_hh + 1 * LB,
        w_ihr + 1 * LW, w_hh + 2 * LW, b_ih + 2 * LB, b_hh + 2 * LB);

    // K2': [L3+L4] diagonal pair, in-place on buf -> buf = h_L4
    lstm_pair34<<<dim3(B_), dim3(512), 0, stream>>>(
        buf, buf,
        w_ihr + 2 * LW, w_hh + 3 * LW, b_ih + 3 * LB, b_hh + 3 * LB,
        w_ihr + 3 * LW, w_hh + 4 * LW, b_ih + 4 * LB, b_hh + 4 * LB);

    mlp_head_v2<<<dim3((B_ * T_) / 256), dim3(256), 0, stream>>>(
        buf, W1, b1, W2, b2, out);
}